// Round 11
// baseline (439.553 us; speedup 1.0000x reference)
//
#include <hip/hip_runtime.h>
#include <hip/hip_bf16.h>
#include <stdint.h>

#define N_NODES  50000
#define N_GRAPHS 256
#define DIM      128
#define N_EDGES  800000
#define K2       256            // fused K = [agg | h]
#define N_STRIPS (N_NODES / 16) // 3125, exact
#define PAD_CAP  64             // max degree slack (mean 16; fixed edge list, no overflow)
#define NBUCKET  196            // ceil(50000/256) buckets of 256 nodes (bucket = dst>>8)
#define NCHUNK   256            // edge chunks
#define CHUNK    3125           // NCHUNK*CHUNK == N_EDGES exactly
#define NSLICE   4              // feature slices of 32 dims; slice buffer = 3.2 MB -> fits XCD L2
#define SLICE_U  (N_NODES * 32) // ushorts per slice

typedef __attribute__((ext_vector_type(8))) short  short8;
typedef __attribute__((ext_vector_type(4))) float  floatx4;

__device__ __forceinline__ ushort f2bf(float f) {
    union { float f; uint32_t u; } c; c.f = f;
    uint32_t u = c.u;
    return (ushort)((u + 0x7fffu + ((u >> 16) & 1u)) >> 16);  // RNE
}
__device__ __forceinline__ float bflo(uint32_t d) {   // low bf16 -> f32
    union { uint32_t u; float f; } c; c.u = d << 16; return c.f;
}
__device__ __forceinline__ float bfhi(uint32_t d) {   // high bf16 -> f32
    union { uint32_t u; float f; } c; c.u = d & 0xffff0000u; return c.f;
}

// ---------- fused prep: x->bf16 (slice-major), weights->Wt, graph bounds ----------
__global__ __launch_bounds__(256) void k_prep(const float* __restrict__ x,
                                              ushort* __restrict__ xbS,
                                              const float* __restrict__ Wl0, const float* __restrict__ Wr0,
                                              const float* __restrict__ Wl1, const float* __restrict__ Wr1,
                                              const float* __restrict__ Wl2, const float* __restrict__ Wr2,
                                              ushort* __restrict__ Wt,
                                              const int* __restrict__ batch,
                                              int* __restrict__ gstart,
                                              int* __restrict__ gend) {
    const int CONV_BLOCKS = (N_NODES * 32 + 255) / 256;          // 6250 (4-dim chunks)
    const int W_BLOCKS    = (3 * DIM * K2 + 255) / 256;          // 384
    int b = blockIdx.x;
    if (b < CONV_BLOCKS) {
        int i = b * 256 + threadIdx.x;                           // chunk of 4 dims
        if (i < N_NODES * 32) {
            int node = i >> 5, c = i & 31;
            float4 v = ((const float4*)x)[(size_t)node * 32 + c];
            uint32_t lo = (uint32_t)f2bf(v.x) | ((uint32_t)f2bf(v.y) << 16);
            uint32_t hi = (uint32_t)f2bf(v.z) | ((uint32_t)f2bf(v.w) << 16);
            int s = c >> 3, off = (c & 7) * 4;                   // slice, in-slice dim offset
            *(uint2*)(xbS + (size_t)s * SLICE_U + node * 32 + off) = make_uint2(lo, hi);
        }
    } else if (b < CONV_BLOCKS + W_BLOCKS) {
        int i = (b - CONV_BLOCKS) * 256 + threadIdx.x;
        if (i < 3 * DIM * K2) {
            int layer = i / (DIM * K2);
            int j = i % (DIM * K2);
            int n = j / K2, k = j % K2;
            const float* Wl = (layer == 0) ? Wl0 : (layer == 1) ? Wl1 : Wl2;
            const float* Wr = (layer == 0) ? Wr0 : (layer == 1) ? Wr1 : Wr2;
            float v = (k < DIM) ? Wl[k * DIM + n] : Wr[(k - DIM) * DIM + n];
            Wt[i] = f2bf(v);
        }
    } else {
        int i = (b - CONV_BLOCKS - W_BLOCKS) * 256 + threadIdx.x;
        if (i < N_NODES) {
            int g = batch[i];
            if (i == 0) gstart[g] = 0;
            int gn = (i + 1 < N_NODES) ? batch[i + 1] : -1;
            if (gn != g) {
                gend[g] = i + 1;
                if (gn >= 0) gstart[gn] = i + 1;
            }
        }
    }
}

// ---------- radix bucket build (no global atomics) ----------
__global__ __launch_bounds__(256) void k_hist(const int* __restrict__ dst,
                                              int* __restrict__ counts) {  // [NCHUNK][NBUCKET]
    __shared__ int hist[NBUCKET];
    int t = threadIdx.x, b = blockIdx.x;
    if (t < NBUCKET) hist[t] = 0;
    __syncthreads();
    const int e0 = b * CHUNK;
    for (int i = t; i < CHUNK; i += 256)
        atomicAdd(&hist[dst[e0 + i] >> 8], 1);
    __syncthreads();
    if (t < NBUCKET) counts[b * NBUCKET + t] = hist[t];
}

__global__ __launch_bounds__(256) void k_scan_col(const int* __restrict__ counts,
                                                  int* __restrict__ off,     // [NCHUNK][NBUCKET]
                                                  int* __restrict__ total) { // [NBUCKET]
    __shared__ int buf[256];
    int t = threadIdx.x, j = blockIdx.x;            // j < NBUCKET
    int v = counts[t * NBUCKET + j];
    buf[t] = v;
    __syncthreads();
    #pragma unroll
    for (int d = 1; d < 256; d <<= 1) {
        int x = (t >= d) ? buf[t - d] : 0;
        __syncthreads();
        buf[t] += x;
        __syncthreads();
    }
    off[t * NBUCKET + j] = buf[t] - v;              // exclusive within column
    if (t == 255) total[j] = buf[255];
}

__global__ __launch_bounds__(256) void k_scan_total(const int* __restrict__ total,
                                                    int* __restrict__ basep) {
    __shared__ int buf[256];
    int t = threadIdx.x;
    int v = (t < NBUCKET) ? total[t] : 0;
    buf[t] = v;
    __syncthreads();
    #pragma unroll
    for (int d = 1; d < 256; d <<= 1) {
        int x = (t >= d) ? buf[t - d] : 0;
        __syncthreads();
        buf[t] += x;
        __syncthreads();
    }
    if (t < NBUCKET) basep[t] = buf[t] - v;         // exclusive
}

__global__ __launch_bounds__(256) void k_scatter(const int* __restrict__ src,
                                                 const int* __restrict__ dst,
                                                 const int* __restrict__ off,
                                                 const int* __restrict__ basep,
                                                 uint32_t* __restrict__ ebuf) {
    __shared__ int cur[NBUCKET];
    int t = threadIdx.x, b = blockIdx.x;
    if (t < NBUCKET) cur[t] = off[b * NBUCKET + t] + basep[t];
    __syncthreads();
    const int e0 = b * CHUNK;
    for (int i = t; i < CHUNK; i += 256) {
        int d = dst[e0 + i];
        int s = src[e0 + i];                         // < 50000 < 2^16
        int p = atomicAdd(&cur[d >> 8], 1);
        ebuf[p] = ((uint32_t)(d & 255) << 16) | (uint32_t)s;
    }
}

__global__ __launch_bounds__(256) void k_build(const uint32_t* __restrict__ ebuf,
                                               const int* __restrict__ total,
                                               const int* __restrict__ basep,
                                               ushort* __restrict__ adj,   // [node][PAD_CAP] ushort ids
                                               int* __restrict__ cnt) {
    __shared__ int lcnt[256];
    int t = threadIdx.x, j = blockIdx.x;
    lcnt[t] = 0;
    __syncthreads();
    int b0 = basep[j], tot = total[j];
    for (int i = t; i < tot; i += 256) {
        uint32_t v = ebuf[b0 + i];
        int dl = (int)(v >> 16);
        int s  = (int)(v & 0xffffu);
        int p  = atomicAdd(&lcnt[dl], 1);
        if (p < PAD_CAP) adj[((size_t)j * 256 + dl) * PAD_CAP + p] = (ushort)s;
    }
    __syncthreads();
    int node = j * 256 + t;
    if (node < N_NODES) cnt[node] = lcnt[t];
}

// ---------- canonicalize adjacency: bitonic sort each node's list across one wave ----------
// Multiset per node is deterministic; sorting makes the summation order (and bf16
// rounding) a deterministic function of the edge set, independent of build order.
__global__ __launch_bounds__(256) void k_sort_adj(ushort* __restrict__ adj,
                                                  const int* __restrict__ cnt) {
    int wid  = threadIdx.x >> 6;
    int lane = threadIdx.x & 63;
    int node = blockIdx.x * 4 + wid;
    if (node >= N_NODES) return;
    int deg = cnt[node];
    int m   = deg < PAD_CAP ? deg : PAD_CAP;
    ushort* lst = adj + (size_t)node * PAD_CAP;
    int v = (lane < m) ? (int)lst[lane] : 0xFFFF;  // pad sorts to the end (ids < 50000)
    #pragma unroll
    for (int k = 2; k <= 64; k <<= 1) {
        #pragma unroll
        for (int j = k >> 1; j > 0; j >>= 1) {
            int other  = __shfl_xor(v, j, 64);
            bool down  = (lane & k) != 0;
            bool lower = (lane & j) == 0;
            v = (lower ^ down) ? min(v, other) : max(v, other);
        }
    }
    if (lane < m) lst[lane] = (ushort)v;           // ascending neighbor ids
}

// ---------- XCD-sliced gather: slice = blockIdx&3 -> XCD {s, s+4} via round-robin ----------
// Each slice buffer (3.2 MB) fits the serving XCD's 4 MB L2, so the random row
// gathers become L2 hits instead of ~1.5 TB/s fabric misses (R7-R10 plateau).
// Wave = one node at a time: 8 lanes x 8B cover the 64B slice row -> 8 edges per
// load inst; 4 loads in flight = 32 edges. Reduce via shfl_xor over edge groups.
__global__ __launch_bounds__(256) void k_gather(const ushort* __restrict__ hS,
                                                const ushort* __restrict__ adj,
                                                const int* __restrict__ cnt,
                                                ushort* __restrict__ aggS) {
    int s    = blockIdx.x & 3;                    // slice (XCD-pinned by dispatch order)
    int nb   = blockIdx.x >> 2;
    int wid  = threadIdx.x >> 6;
    int lane = threadIdx.x & 63;
    int g    = lane >> 3;                         // edge group 0..7
    int l8   = lane & 7;                          // 8B slot in 64B row (4 dims)
    const ushort* hs = hS + (size_t)s * SLICE_U;
    ushort* as = aggS + (size_t)s * SLICE_U;
    int node0 = (nb * 4 + wid) * 16;              // 16 nodes per wave, serial

    for (int j = 0; j < 16; ++j) {
        int node = node0 + j;
        if (node >= N_NODES) return;              // 50000 % 16 == 0: whole wave exits
        int deg = cnt[node];
        int m   = deg < PAD_CAP ? deg : PAD_CAP;
        int vidx = (int)adj[(size_t)node * PAD_CAP + lane];  // whole list in lanes
        float a0 = 0.f, a1 = 0.f, a2 = 0.f, a3 = 0.f;
        for (int base = 0; base < m; base += 32) {
            uint2 v[4];
            #pragma unroll
            for (int k = 0; k < 4; ++k) {
                int e  = base + k * 8 + g;        // <= 63 always
                int ec = e < m ? e : m - 1;
                int nbr = __builtin_amdgcn_ds_bpermute(ec << 2, vidx);
                v[k] = *(const uint2*)(hs + (size_t)nbr * 32 + l8 * 4);
            }
            #pragma unroll
            for (int k = 0; k < 4; ++k) {
                int e = base + k * 8 + g;
                uint32_t dx = (e < m) ? v[k].x : 0u;
                uint32_t dy = (e < m) ? v[k].y : 0u;
                a0 += bflo(dx); a1 += bfhi(dx);
                a2 += bflo(dy); a3 += bfhi(dy);
            }
        }
        #pragma unroll
        for (int msk = 8; msk <= 32; msk <<= 1) { // combine 8 edge groups
            a0 += __shfl_xor(a0, msk, 64);
            a1 += __shfl_xor(a1, msk, 64);
            a2 += __shfl_xor(a2, msk, 64);
            a3 += __shfl_xor(a3, msk, 64);
        }
        if (lane < 8) {                           // lanes 0..7 write the 64B row
            float inv = 1.0f / (float)(deg > 0 ? deg : 1);
            uint32_t w0 = (uint32_t)f2bf(a0 * inv) | ((uint32_t)f2bf(a1 * inv) << 16);
            uint32_t w1 = (uint32_t)f2bf(a2 * inv) | ((uint32_t)f2bf(a3 * inv) << 16);
            *(uint2*)(as + (size_t)node * 32 + lane * 4) = make_uint2(w0, w1);
        }
    }
}

// ---------- SAGE GEMM: h_out = relu([agg|h] @ [Wl;Wr] + bl), slice-major A ----------
template <bool OUT_F32>
__global__ __launch_bounds__(256) void k_gemm(const ushort* __restrict__ aggS,
                                              const ushort* __restrict__ hS,
                                              const ushort* __restrict__ Wt,
                                              const float* __restrict__ bias,
                                              ushort* __restrict__ outS,
                                              float* __restrict__ out_f) {
    int wid   = threadIdx.x >> 6;
    int lane  = threadIdx.x & 63;
    int strip = blockIdx.x * 4 + wid;
    if (strip >= N_STRIPS) return;
    int r0   = strip * 16;
    int row  = lane & 15;
    int quad = lane >> 4;
    int mrow = r0 + row;

    // A frags: lane holds A[m=lane&15][k=quad*8+j]; chunk c=quad*8+ks*32 -> slice ks, off quad*8
    short8 a[8];
    #pragma unroll
    for (int ks = 0; ks < 4; ++ks)
        a[ks] = *(const short8*)(aggS + (size_t)ks * SLICE_U + mrow * 32 + quad * 8);
    #pragma unroll
    for (int ks = 0; ks < 4; ++ks)
        a[4 + ks] = *(const short8*)(hS + (size_t)ks * SLICE_U + mrow * 32 + quad * 8);

    #pragma unroll
    for (int ct = 0; ct < 8; ++ct) {
        int col = ct * 16 + row;
        const ushort* wrow = Wt + (size_t)col * K2 + quad * 8;
        floatx4 acc = {0.f, 0.f, 0.f, 0.f};
        #pragma unroll
        for (int ks = 0; ks < 8; ++ks) {
            short8 b = *(const short8*)(wrow + ks * 32);
            acc = __builtin_amdgcn_mfma_f32_16x16x32_bf16(a[ks], b, acc, 0, 0, 0);
        }
        float bv = bias[col];
        #pragma unroll
        for (int r = 0; r < 4; ++r) {
            int m = r0 + quad * 4 + r;            // C/D: col=lane&15, row=quad*4+reg
            float v = acc[r] + bv;
            v = v > 0.f ? v : 0.f;
            if (OUT_F32) out_f[(size_t)m * DIM + col] = v;                     // row-major fp32
            else outS[(size_t)(col >> 5) * SLICE_U + m * 32 + (col & 31)] = f2bf(v); // slice-major
        }
    }
}

// ---------- mean/max readout (batch sorted -> run-length flush) ----------
__global__ __launch_bounds__(128) void k_readout(const float* __restrict__ h,
                                                 const int* __restrict__ batch,
                                                 float* __restrict__ out) {
    int d  = threadIdx.x;                 // 0..127
    int n0 = blockIdx.x * 128;
    int n1 = min(n0 + 128, N_NODES);
    int cur = -1; float sum = 0.f, mx = 0.f;
    for (int i = n0; i < n1; ++i) {
        int g = batch[i];                 // block-uniform
        if (g != cur) {
            if (cur >= 0) {
                atomicAdd(&out[cur * 2 * DIM + d], sum);
                atomicMax((int*)&out[cur * 2 * DIM + DIM + d], __float_as_int(mx));
            }
            cur = g; sum = 0.f; mx = 0.f;
        }
        float v = h[(size_t)i * DIM + d];
        sum += v; mx = fmaxf(mx, v);
    }
    if (cur >= 0) {
        atomicAdd(&out[cur * 2 * DIM + d], sum);
        atomicMax((int*)&out[cur * 2 * DIM + DIM + d], __float_as_int(mx));
    }
}

__global__ __launch_bounds__(256) void k_finalize(float* __restrict__ out,
                                                  const int* __restrict__ gstart,
                                                  const int* __restrict__ gend) {
    int i = blockIdx.x * 256 + threadIdx.x;
    if (i < N_GRAPHS * DIM) {
        int g = i / DIM, d = i % DIM;
        int c = gend[g] - gstart[g];
        out[g * 2 * DIM + d] /= (float)(c > 0 ? c : 1);
    }
}

extern "C" void kernel_launch(void* const* d_in, const int* in_sizes, int n_in,
                              void* d_out, int out_size, void* d_ws, size_t ws_size,
                              hipStream_t stream) {
    const float* x     = (const float*)d_in[0];
    const int*   ei    = (const int*)d_in[1];
    const int*   src   = ei;
    const int*   dst   = ei + N_EDGES;
    const int*   batch = (const int*)d_in[2];
    const float* Wl[3] = {(const float*)d_in[3], (const float*)d_in[6], (const float*)d_in[9]};
    const float* bl[3] = {(const float*)d_in[4], (const float*)d_in[7], (const float*)d_in[10]};
    const float* Wr[3] = {(const float*)d_in[5], (const float*)d_in[8], (const float*)d_in[11]};
    float* out = (float*)d_out;

    char* base = (char*)d_ws;
    size_t o = 0;
    auto alloc = [&](size_t b) -> char* {
        char* p = base + o;
        o = (o + b + 255) & ~(size_t)255;
        return p;
    };
    int*     gstart = (int*)alloc((size_t)N_GRAPHS * 4);
    int*     gend   = (int*)alloc((size_t)N_GRAPHS * 4);
    size_t   zero_bytes = o;                      // gstart+gend contiguous
    int*     cnt    = (int*)alloc((size_t)N_NODES * 4);
    int*     counts = (int*)alloc((size_t)NCHUNK * NBUCKET * 4);
    int*     offs   = (int*)alloc((size_t)NCHUNK * NBUCKET * 4);
    int*     total  = (int*)alloc((size_t)NBUCKET * 4);
    int*     basep  = (int*)alloc((size_t)NBUCKET * 4);
    uint32_t* ebuf  = (uint32_t*)alloc((size_t)N_EDGES * 4);
    ushort*  adj    = (ushort*)alloc((size_t)N_NODES * PAD_CAP * 2); // 6.4 MB
    ushort*  xbS    = (ushort*)alloc((size_t)N_NODES * DIM * 2);     // slice-major
    ushort*  haS    = (ushort*)alloc((size_t)N_NODES * DIM * 2);
    ushort*  hbS    = (ushort*)alloc((size_t)N_NODES * DIM * 2);
    ushort*  aggS   = (ushort*)alloc((size_t)N_NODES * DIM * 2);
    float*   h3     = (float*)alloc((size_t)N_NODES * DIM * 4);      // row-major fp32
    ushort*  Wt     = (ushort*)alloc((size_t)3 * DIM * K2 * 2);
    (void)ws_size; (void)n_in; (void)in_sizes;

    hipMemsetAsync(base, 0, zero_bytes, stream);
    hipMemsetAsync(d_out, 0, (size_t)out_size * 4, stream);

    const int CONV_BLOCKS = (N_NODES * 32 + 255) / 256;
    const int W_BLOCKS    = (3 * DIM * K2 + 255) / 256;
    const int GB_BLOCKS   = (N_NODES + 255) / 256;
    k_prep<<<CONV_BLOCKS + W_BLOCKS + GB_BLOCKS, 256, 0, stream>>>(
        x, xbS, Wl[0], Wr[0], Wl[1], Wr[1], Wl[2], Wr[2], Wt, batch, gstart, gend);

    k_hist<<<NCHUNK, 256, 0, stream>>>(dst, counts);
    k_scan_col<<<NBUCKET, 256, 0, stream>>>(counts, offs, total);
    k_scan_total<<<1, 256, 0, stream>>>(total, basep);
    k_scatter<<<NCHUNK, 256, 0, stream>>>(src, dst, offs, basep, ebuf);
    k_build<<<NBUCKET, 256, 0, stream>>>(ebuf, total, basep, adj, cnt);
    k_sort_adj<<<(N_NODES + 3) / 4, 256, 0, stream>>>(adj, cnt);

    const int GGRID = NSLICE * ((N_NODES + 63) / 64);   // 4 slices x 782 node-blocks
    const int MGRID = (N_STRIPS + 3) / 4;               // 782

    // layer 0
    k_gather<<<GGRID, 256, 0, stream>>>(xbS, adj, cnt, aggS);
    k_gemm<false><<<MGRID, 256, 0, stream>>>(aggS, xbS, Wt,                bl[0], haS, nullptr);
    // layer 1
    k_gather<<<GGRID, 256, 0, stream>>>(haS, adj, cnt, aggS);
    k_gemm<false><<<MGRID, 256, 0, stream>>>(aggS, haS, Wt + DIM * K2,     bl[1], hbS, nullptr);
    // layer 2 (fp32 row-major output for readout accuracy)
    k_gather<<<GGRID, 256, 0, stream>>>(hbS, adj, cnt, aggS);
    k_gemm<true ><<<MGRID, 256, 0, stream>>>(aggS, hbS, Wt + 2 * DIM * K2, bl[2], nullptr, h3);

    k_readout<<<(N_NODES + 127) / 128, 128, 0, stream>>>(h3, batch, out);
    k_finalize<<<(N_GRAPHS * DIM + 255) / 256, 256, 0, stream>>>(out, gstart, gend);
}

// Round 12
// 369.967 us; speedup vs baseline: 1.1881x; 1.1881x over previous
//
#include <hip/hip_runtime.h>
#include <hip/hip_bf16.h>
#include <stdint.h>

#define N_NODES  50000
#define N_GRAPHS 256
#define DIM      128
#define N_EDGES  800000
#define K2       256            // fused K = [agg | h]
#define N_STRIPS (N_NODES / 16) // 3125, exact
#define PAD_CAP  64             // max degree slack (mean 16; fixed edge list, no overflow)
#define NBUCKET  196            // ceil(50000/256) buckets of 256 nodes (bucket = dst>>8)
#define NCHUNK   256            // edge chunks
#define CHUNK    3125           // NCHUNK*CHUNK == N_EDGES exactly
#define DUMMY    50000          // zero-row node id used to pad adjacency (no predication needed)
#define NPAD     (N_NODES + 1)  // h buffers carry the dummy row

typedef __attribute__((ext_vector_type(8))) short  short8;
typedef __attribute__((ext_vector_type(4))) float  floatx4;

__device__ __forceinline__ ushort f2bf(float f) {
    union { float f; uint32_t u; } c; c.f = f;
    uint32_t u = c.u;
    return (ushort)((u + 0x7fffu + ((u >> 16) & 1u)) >> 16);  // RNE
}
__device__ __forceinline__ float bflo(uint32_t d) {   // low bf16 -> f32 (1 shl)
    union { uint32_t u; float f; } c; c.u = d << 16; return c.f;
}
__device__ __forceinline__ float bfhi(uint32_t d) {   // high bf16 -> f32 (1 and)
    union { uint32_t u; float f; } c; c.u = d & 0xffff0000u; return c.f;
}

// ---------- fused prep: x->bf16, weights->Wt, graph bounds, dummy-row zero ----------
__global__ __launch_bounds__(256) void k_prep(const float* __restrict__ x,
                                              ushort* __restrict__ xb,
                                              const float* __restrict__ Wl0, const float* __restrict__ Wr0,
                                              const float* __restrict__ Wl1, const float* __restrict__ Wr1,
                                              const float* __restrict__ Wl2, const float* __restrict__ Wr2,
                                              ushort* __restrict__ Wt,
                                              const int* __restrict__ batch,
                                              int* __restrict__ gstart,
                                              int* __restrict__ gend,
                                              ushort* __restrict__ ha,
                                              ushort* __restrict__ hb) {
    const int CONV_BLOCKS = (N_NODES * DIM / 4 + 255) / 256;     // 6250
    const int W_BLOCKS    = (3 * DIM * K2 + 255) / 256;          // 384
    const int GB_BLOCKS   = (N_NODES + 255) / 256;               // 196
    int b = blockIdx.x;
    if (b < CONV_BLOCKS) {
        int i = b * 256 + threadIdx.x;
        const int n4 = N_NODES * DIM / 4;
        if (i < n4) {
            float4 v = ((const float4*)x)[i];
            uint32_t lo = (uint32_t)f2bf(v.x) | ((uint32_t)f2bf(v.y) << 16);
            uint32_t hi = (uint32_t)f2bf(v.z) | ((uint32_t)f2bf(v.w) << 16);
            ((uint2*)xb)[i] = make_uint2(lo, hi);
        }
    } else if (b < CONV_BLOCKS + W_BLOCKS) {
        int i = (b - CONV_BLOCKS) * 256 + threadIdx.x;
        if (i < 3 * DIM * K2) {
            int layer = i / (DIM * K2);
            int j = i % (DIM * K2);
            int n = j / K2, k = j % K2;
            const float* Wl = (layer == 0) ? Wl0 : (layer == 1) ? Wl1 : Wl2;
            const float* Wr = (layer == 0) ? Wr0 : (layer == 1) ? Wr1 : Wr2;
            float v = (k < DIM) ? Wl[k * DIM + n] : Wr[(k - DIM) * DIM + n];
            Wt[i] = f2bf(v);
        }
    } else if (b < CONV_BLOCKS + W_BLOCKS + GB_BLOCKS) {
        int i = (b - CONV_BLOCKS - W_BLOCKS) * 256 + threadIdx.x;
        if (i < N_NODES) {
            int g = batch[i];
            if (i == 0) gstart[g] = 0;
            int gn = (i + 1 < N_NODES) ? batch[i + 1] : -1;
            if (gn != g) {
                gend[g] = i + 1;
                if (gn >= 0) gstart[gn] = i + 1;
            }
        }
    } else {
        // zero the dummy row (id 50000) of xb/ha/hb: 3 rows x 64 dwords
        int t = threadIdx.x;
        if (t < 192) {
            ushort* buf = (t < 64) ? xb : (t < 128) ? ha : hb;
            ((uint32_t*)(buf + (size_t)DUMMY * DIM))[t & 63] = 0u;
        }
    }
}

// ---------- radix bucket build (no global atomics) ----------
__global__ __launch_bounds__(256) void k_hist(const int* __restrict__ dst,
                                              int* __restrict__ counts) {  // [NCHUNK][NBUCKET]
    __shared__ int hist[NBUCKET];
    int t = threadIdx.x, b = blockIdx.x;
    if (t < NBUCKET) hist[t] = 0;
    __syncthreads();
    const int e0 = b * CHUNK;
    for (int i = t; i < CHUNK; i += 256)
        atomicAdd(&hist[dst[e0 + i] >> 8], 1);
    __syncthreads();
    if (t < NBUCKET) counts[b * NBUCKET + t] = hist[t];
}

__global__ __launch_bounds__(256) void k_scan_col(const int* __restrict__ counts,
                                                  int* __restrict__ off,     // [NCHUNK][NBUCKET]
                                                  int* __restrict__ total) { // [NBUCKET]
    __shared__ int buf[256];
    int t = threadIdx.x, j = blockIdx.x;            // j < NBUCKET
    int v = counts[t * NBUCKET + j];
    buf[t] = v;
    __syncthreads();
    #pragma unroll
    for (int d = 1; d < 256; d <<= 1) {
        int x = (t >= d) ? buf[t - d] : 0;
        __syncthreads();
        buf[t] += x;
        __syncthreads();
    }
    off[t * NBUCKET + j] = buf[t] - v;              // exclusive within column
    if (t == 255) total[j] = buf[255];
}

__global__ __launch_bounds__(256) void k_scan_total(const int* __restrict__ total,
                                                    int* __restrict__ basep) {
    __shared__ int buf[256];
    int t = threadIdx.x;
    int v = (t < NBUCKET) ? total[t] : 0;
    buf[t] = v;
    __syncthreads();
    #pragma unroll
    for (int d = 1; d < 256; d <<= 1) {
        int x = (t >= d) ? buf[t - d] : 0;
        __syncthreads();
        buf[t] += x;
        __syncthreads();
    }
    if (t < NBUCKET) basep[t] = buf[t] - v;         // exclusive
}

__global__ __launch_bounds__(256) void k_scatter(const int* __restrict__ src,
                                                 const int* __restrict__ dst,
                                                 const int* __restrict__ off,
                                                 const int* __restrict__ basep,
                                                 uint32_t* __restrict__ ebuf) {
    __shared__ int cur[NBUCKET];
    int t = threadIdx.x, b = blockIdx.x;
    if (t < NBUCKET) cur[t] = off[b * NBUCKET + t] + basep[t];
    __syncthreads();
    const int e0 = b * CHUNK;
    for (int i = t; i < CHUNK; i += 256) {
        int d = dst[e0 + i];
        int s = src[e0 + i];                         // < 50000 < 2^16
        int p = atomicAdd(&cur[d >> 8], 1);
        ebuf[p] = ((uint32_t)(d & 255) << 16) | (uint32_t)s;
    }
}

__global__ __launch_bounds__(256) void k_build(const uint32_t* __restrict__ ebuf,
                                               const int* __restrict__ total,
                                               const int* __restrict__ basep,
                                               ushort* __restrict__ adj,
                                               int* __restrict__ cnt) {
    __shared__ int lcnt[256];
    int t = threadIdx.x, j = blockIdx.x;
    lcnt[t] = 0;
    __syncthreads();
    int b0 = basep[j], tot = total[j];
    for (int i = t; i < tot; i += 256) {
        uint32_t v = ebuf[b0 + i];
        int dl = (int)(v >> 16);
        int s  = (int)(v & 0xffffu);
        int p  = atomicAdd(&lcnt[dl], 1);
        if (p < PAD_CAP) adj[((size_t)j * 256 + dl) * PAD_CAP + p] = (ushort)s;
    }
    __syncthreads();
    int node = j * 256 + t;
    if (node < N_NODES) cnt[node] = lcnt[t];
}

// ---------- canonicalize adjacency: bitonic sort + dummy-pad each node's list ----------
// Multiset per node is deterministic; sorting makes the summation order (and bf16
// rounding) a deterministic function of the edge set. Pad lanes get DUMMY (zero
// row), so the aggregate needs NO per-edge predication.
__global__ __launch_bounds__(256) void k_sort_adj(ushort* __restrict__ adj,
                                                  const int* __restrict__ cnt) {
    int wid  = threadIdx.x >> 6;
    int lane = threadIdx.x & 63;
    int node = blockIdx.x * 4 + wid;
    if (node >= N_NODES) return;
    int deg = cnt[node];
    int m   = deg < PAD_CAP ? deg : PAD_CAP;
    ushort* lst = adj + (size_t)node * PAD_CAP;
    int v = (lane < m) ? (int)lst[lane] : DUMMY;   // DUMMY > all real ids -> sorts to end
    #pragma unroll
    for (int k = 2; k <= 64; k <<= 1) {
        #pragma unroll
        for (int j = k >> 1; j > 0; j >>= 1) {
            int other  = __shfl_xor(v, j, 64);
            bool down  = (lane & k) != 0;
            bool lower = (lane & j) == 0;
            v = (lower ^ down) ? min(v, other) : max(v, other);
        }
    }
    lst[lane] = (ushort)v;                         // all 64 lanes valid now
}

// ---------- neighbor mean aggregation: one wave per node, zero predication ----------
// mq = deg rounded up to 8 (pad entries are DUMMY -> zero row, hot L1 line).
// Per edge: 1 coalesced row-load (dword/lane over 256B) + shl/and/2add. Neighbor
// ids forced scalar via readfirstlane.
__global__ __launch_bounds__(256) void k_aggregate(const ushort* __restrict__ h_in,
                                                   const ushort* __restrict__ adj,
                                                   const int* __restrict__ cnt,
                                                   ushort* __restrict__ agg) {
    int wid  = threadIdx.x >> 6;
    int lane = threadIdx.x & 63;
    int node = blockIdx.x * 4 + wid;
    int deg  = cnt[node];
    int mq   = (deg + 7) & ~7;                     // <= PAD_CAP
    const ushort* lst = adj + (size_t)node * PAD_CAP;
    const uint32_t* hw = (const uint32_t*)h_in;    // 64 dwords per row
    float ax[4] = {0.f, 0.f, 0.f, 0.f};
    float ay[4] = {0.f, 0.f, 0.f, 0.f};
    for (int e = 0; e < mq; e += 8) {
        int idx[8];
        uint32_t v[8];
        #pragma unroll
        for (int k = 0; k < 8; ++k)
            idx[k] = __builtin_amdgcn_readfirstlane((int)lst[e + k]);  // scalar addr math
        #pragma unroll
        for (int k = 0; k < 8; ++k)
            v[k] = hw[(size_t)idx[k] * 64 + lane]; // 8 coalesced 256B rows in flight
        #pragma unroll
        for (int k = 0; k < 8; ++k) {
            ax[k & 3] += bflo(v[k]);
            ay[k & 3] += bfhi(v[k]);
        }
    }
    float axs = (ax[0] + ax[1]) + (ax[2] + ax[3]);
    float ays = (ay[0] + ay[1]) + (ay[2] + ay[3]);
    float inv = 1.0f / (float)(deg > 0 ? deg : 1);
    uint32_t o = (uint32_t)f2bf(axs * inv) | ((uint32_t)f2bf(ays * inv) << 16);
    ((uint32_t*)(agg + (size_t)node * DIM))[lane] = o;
}

// ---------- SAGE GEMM: h_out = relu([agg|h] @ [Wl;Wr] + bl), row-major ----------
template <bool OUT_F32>
__global__ __launch_bounds__(256) void k_gemm(const ushort* __restrict__ agg,
                                              const ushort* __restrict__ h_in,
                                              const ushort* __restrict__ Wt,
                                              const float* __restrict__ bias,
                                              ushort* __restrict__ out_bf,
                                              float* __restrict__ out_f) {
    int wid   = threadIdx.x >> 6;
    int lane  = threadIdx.x & 63;
    int strip = blockIdx.x * 4 + wid;
    if (strip >= N_STRIPS) return;
    int r0   = strip * 16;
    int row  = lane & 15;
    int quad = lane >> 4;
    int mrow = r0 + row;

    // A fragments: lane holds A[m=lane&15][k=quad*8+j], j=0..7  (16B contiguous)
    short8 a[8];
    const ushort* arow = agg  + (size_t)mrow * DIM + quad * 8;
    const ushort* hrow = h_in + (size_t)mrow * DIM + quad * 8;
    #pragma unroll
    for (int ks = 0; ks < 4; ++ks) a[ks]     = *(const short8*)(arow + ks * 32);
    #pragma unroll
    for (int ks = 0; ks < 4; ++ks) a[4 + ks] = *(const short8*)(hrow + ks * 32);

    #pragma unroll
    for (int ct = 0; ct < 8; ++ct) {
        int col = ct * 16 + row;
        const ushort* wrow = Wt + (size_t)col * K2 + quad * 8;
        floatx4 acc = {0.f, 0.f, 0.f, 0.f};
        #pragma unroll
        for (int ks = 0; ks < 8; ++ks) {
            short8 b = *(const short8*)(wrow + ks * 32);
            acc = __builtin_amdgcn_mfma_f32_16x16x32_bf16(a[ks], b, acc, 0, 0, 0);
        }
        float bv = bias[col];
        #pragma unroll
        for (int r = 0; r < 4; ++r) {
            int m = r0 + quad * 4 + r;            // C/D: col=lane&15, row=quad*4+reg
            float v = acc[r] + bv;
            v = v > 0.f ? v : 0.f;
            if (OUT_F32) out_f[(size_t)m * DIM + col] = v;
            else         out_bf[(size_t)m * DIM + col] = f2bf(v);
        }
    }
}

// ---------- mean/max readout (batch sorted -> run-length flush) ----------
__global__ __launch_bounds__(128) void k_readout(const float* __restrict__ h,
                                                 const int* __restrict__ batch,
                                                 float* __restrict__ out) {
    int d  = threadIdx.x;                 // 0..127
    int n0 = blockIdx.x * 128;
    int n1 = min(n0 + 128, N_NODES);
    int cur = -1; float sum = 0.f, mx = 0.f;
    for (int i = n0; i < n1; ++i) {
        int g = batch[i];                 // block-uniform
        if (g != cur) {
            if (cur >= 0) {
                atomicAdd(&out[cur * 2 * DIM + d], sum);
                atomicMax((int*)&out[cur * 2 * DIM + DIM + d], __float_as_int(mx));
            }
            cur = g; sum = 0.f; mx = 0.f;
        }
        float v = h[(size_t)i * DIM + d];
        sum += v; mx = fmaxf(mx, v);
    }
    if (cur >= 0) {
        atomicAdd(&out[cur * 2 * DIM + d], sum);
        atomicMax((int*)&out[cur * 2 * DIM + DIM + d], __float_as_int(mx));
    }
}

__global__ __launch_bounds__(256) void k_finalize(float* __restrict__ out,
                                                  const int* __restrict__ gstart,
                                                  const int* __restrict__ gend) {
    int i = blockIdx.x * 256 + threadIdx.x;
    if (i < N_GRAPHS * DIM) {
        int g = i / DIM, d = i % DIM;
        int c = gend[g] - gstart[g];
        out[g * 2 * DIM + d] /= (float)(c > 0 ? c : 1);
    }
}

extern "C" void kernel_launch(void* const* d_in, const int* in_sizes, int n_in,
                              void* d_out, int out_size, void* d_ws, size_t ws_size,
                              hipStream_t stream) {
    const float* x     = (const float*)d_in[0];
    const int*   ei    = (const int*)d_in[1];
    const int*   src   = ei;
    const int*   dst   = ei + N_EDGES;
    const int*   batch = (const int*)d_in[2];
    const float* Wl[3] = {(const float*)d_in[3], (const float*)d_in[6], (const float*)d_in[9]};
    const float* bl[3] = {(const float*)d_in[4], (const float*)d_in[7], (const float*)d_in[10]};
    const float* Wr[3] = {(const float*)d_in[5], (const float*)d_in[8], (const float*)d_in[11]};
    float* out = (float*)d_out;

    char* base = (char*)d_ws;
    size_t o = 0;
    auto alloc = [&](size_t b) -> char* {
        char* p = base + o;
        o = (o + b + 255) & ~(size_t)255;
        return p;
    };
    int*     gstart = (int*)alloc((size_t)N_GRAPHS * 4);
    int*     gend   = (int*)alloc((size_t)N_GRAPHS * 4);
    size_t   zero_bytes = o;                      // gstart+gend contiguous
    int*     cnt    = (int*)alloc((size_t)N_NODES * 4);
    int*     counts = (int*)alloc((size_t)NCHUNK * NBUCKET * 4);
    int*     offs   = (int*)alloc((size_t)NCHUNK * NBUCKET * 4);
    int*     total  = (int*)alloc((size_t)NBUCKET * 4);
    int*     basep  = (int*)alloc((size_t)NBUCKET * 4);
    uint32_t* ebuf  = (uint32_t*)alloc((size_t)N_EDGES * 4);
    ushort*  adj    = (ushort*)alloc((size_t)N_NODES * PAD_CAP * 2); // 6.4 MB
    ushort*  xb     = (ushort*)alloc((size_t)NPAD * DIM * 2);        // + dummy row
    ushort*  ha     = (ushort*)alloc((size_t)NPAD * DIM * 2);
    ushort*  hb     = (ushort*)alloc((size_t)NPAD * DIM * 2);
    ushort*  agg    = (ushort*)alloc((size_t)N_NODES * DIM * 2);
    float*   h3     = (float*)alloc((size_t)N_NODES * DIM * 4);
    ushort*  Wt     = (ushort*)alloc((size_t)3 * DIM * K2 * 2);
    (void)ws_size; (void)n_in; (void)in_sizes;

    hipMemsetAsync(base, 0, zero_bytes, stream);
    hipMemsetAsync(d_out, 0, (size_t)out_size * 4, stream);

    const int CONV_BLOCKS = (N_NODES * DIM / 4 + 255) / 256;
    const int W_BLOCKS    = (3 * DIM * K2 + 255) / 256;
    const int GB_BLOCKS   = (N_NODES + 255) / 256;
    k_prep<<<CONV_BLOCKS + W_BLOCKS + GB_BLOCKS + 1, 256, 0, stream>>>(
        x, xb, Wl[0], Wr[0], Wl[1], Wr[1], Wl[2], Wr[2], Wt, batch, gstart, gend, ha, hb);

    k_hist<<<NCHUNK, 256, 0, stream>>>(dst, counts);
    k_scan_col<<<NBUCKET, 256, 0, stream>>>(counts, offs, total);
    k_scan_total<<<1, 256, 0, stream>>>(total, basep);
    k_scatter<<<NCHUNK, 256, 0, stream>>>(src, dst, offs, basep, ebuf);
    k_build<<<NBUCKET, 256, 0, stream>>>(ebuf, total, basep, adj, cnt);
    k_sort_adj<<<(N_NODES + 3) / 4, 256, 0, stream>>>(adj, cnt);

    const int aggGrid  = N_NODES / 4;             // 12500, exact
    const int gemmGrid = (N_STRIPS + 3) / 4;      // 782

    // layer 0
    k_aggregate<<<aggGrid, 256, 0, stream>>>(xb, adj, cnt, agg);
    k_gemm<false><<<gemmGrid, 256, 0, stream>>>(agg, xb, Wt, bl[0], ha, nullptr);
    // layer 1
    k_aggregate<<<aggGrid, 256, 0, stream>>>(ha, adj, cnt, agg);
    k_gemm<false><<<gemmGrid, 256, 0, stream>>>(agg, ha, Wt + DIM * K2, bl[1], hb, nullptr);
    // layer 2 (fp32 output for readout accuracy)
    k_aggregate<<<aggGrid, 256, 0, stream>>>(hb, adj, cnt, agg);
    k_gemm<true><<<gemmGrid, 256, 0, stream>>>(agg, hb, Wt + 2 * DIM * K2, bl[2], nullptr, h3);

    k_readout<<<(N_NODES + 127) / 128, 128, 0, stream>>>(h3, batch, out);
    k_finalize<<<(N_GRAPHS * DIM + 255) / 256, 256, 0, stream>>>(out, gstart, gend);
}